// Round 4
// baseline (3948.427 us; speedup 1.0000x reference)
//
#include <hip/hip_runtime.h>
#include <stdint.h>

#define T_STEPS 256
#define B_DIM   64
#define MDIM    512
#define NROWS   (T_STEPS * B_DIM)   // 16384
#define KCAT    1024                // [inputs | emb_s]
#define NBIG    3072                // 4M (iou) + M (ctx) + M (wcs)
#define W2ROWS  2560                // 5 gates * 512
#define NBLK2   32                  // persistent phase-2 blocks
#define OUT_N   ((size_t)T_STEPS * B_DIM * MDIM)  // 8388608

typedef short v8s __attribute__((ext_vector_type(8)));
typedef float v4f __attribute__((ext_vector_type(4)));
typedef unsigned long long u64;

static __device__ __forceinline__ unsigned short f2bf(float f) {
    unsigned u = __builtin_bit_cast(unsigned, f);
    u += 0x7FFFu + ((u >> 16) & 1u);            // RNE
    return (unsigned short)(u >> 16);
}
static __device__ __forceinline__ float bf2f(unsigned short h) {
    unsigned u = ((unsigned)h) << 16;
    return __builtin_bit_cast(float, u);
}
// fast transcendentals: v_rcp (~1ulp) + v_exp; rel err ~1e-6, far below the
// bf16 h-quantization noise (absmax 0.0195 vs threshold 0.0565)
static __device__ __forceinline__ float fast_rcp(float x) {
    return __builtin_amdgcn_rcpf(x);
}
static __device__ __forceinline__ float sigmoid_fast(float x) {
    return fast_rcp(1.0f + __expf(-x));
}
static __device__ __forceinline__ float tanh_fast(float x) {
    return 1.0f - 2.0f * fast_rcp(1.0f + __expf(2.0f * x));
}

// ---------------- prepack kernels ----------------

__global__ void pack_xcat(const float* __restrict__ x, const float* __restrict__ s,
                          unsigned short* __restrict__ xcat) {
    int idx = blockIdx.x * blockDim.x + threadIdx.x;   // over NROWS*KCAT
    if (idx >= NROWS * KCAT) return;
    int row = idx >> 10, col = idx & 1023;
    float v = (col < 512) ? x[row * 512 + col] : s[row * 512 + (col - 512)];
    xcat[idx] = f2bf(v);
}

__global__ void pack_wbig(const float* __restrict__ Wioux, const float* __restrict__ bioux,
                          const float* __restrict__ Wious, const float* __restrict__ bious,
                          const float* __restrict__ Wfx,   const float* __restrict__ bfx,
                          const float* __restrict__ Wwc,   const float* __restrict__ bwc,
                          unsigned short* __restrict__ wbig, float* __restrict__ bbig) {
    int idx = blockIdx.x * blockDim.x + threadIdx.x;   // over NBIG*KCAT
    if (idx >= NBIG * KCAT) return;
    int r = idx >> 10, c = idx & 1023;
    float v;
    if (r < 2048)      v = (c < 512) ? Wioux[r * 512 + c] : Wious[r * 512 + (c - 512)];
    else if (r < 2560) { int j = r - 2048; v = (c < 512) ? Wfx[j * 512 + c] : 0.0f; }
    else               { int j = r - 2560; v = (c < 512) ? 0.0f : Wwc[j * 512 + (c - 512)]; }
    wbig[idx] = f2bf(v);
    if (c == 0) {
        float b;
        if (r < 2048)      b = bioux[r] + bious[r];
        else if (r < 2560) b = bfx[r - 2048];
        else               b = bwc[r - 2560];
        bbig[r] = b;
    }
}

// Pack recurrent weights: block bk owns m-cols [16*bk,16*bk+16):
// 5 n-tiles of 16 rows: g=0..3 -> W_iouh rows g*512+m ; g=4 -> W_fh row m
__global__ void pack_w2(const float* __restrict__ Wiouh, const float* __restrict__ biouh,
                        const float* __restrict__ Wfh,   const float* __restrict__ bfh,
                        unsigned short* __restrict__ w2, float* __restrict__ b2) {
    int idx = blockIdx.x * blockDim.x + threadIdx.x;   // over W2ROWS*512
    if (idx >= W2ROWS * 512) return;
    int r = idx >> 9, k = idx & 511;
    int bk = r / 80, rem = r % 80, g = rem >> 4, j = rem & 15;
    int m = bk * 16 + j;
    float v, bias;
    if (g < 4) { v = Wiouh[(size_t)(g * 512 + m) * 512 + k]; bias = biouh[g * 512 + m]; }
    else       { v = Wfh[(size_t)m * 512 + k];               bias = bfh[m]; }
    w2[idx] = f2bf(v);
    if (k == 0) b2[r] = bias;
}

// Tagged h state: u32 word = (step_tag << 16) | bf16(h), row-major [64][512].
// buf0 = h(0) with tag 0; buf1 poisoned with tag 0xFFFF (never matches 1..256)
// so uninitialized-workspace garbage can't alias a future tag.
__global__ void init_state(const float* __restrict__ h0,
                           unsigned* __restrict__ hs0,
                           unsigned* __restrict__ hs1) {
    int idx = blockIdx.x * blockDim.x + threadIdx.x;   // 32768
    if (idx >= B_DIM * MDIM) return;
    hs0[idx] = (unsigned)f2bf(h0[idx]);                // tag 0 in hi16
    hs1[idx] = 0xFFFF0000u;
}

// ---------------- phase 1: big GEMM, output pre-swizzled into per-(t,block) slabs ----------------
// ytile layout: [T][32 bk][64 b][6 slot][16 col] bf16 ; slot 0..3 = iou gates, 4 = ctx, 5 = wcs(tanh).
// Each (t,bk) slab is 12 KB contiguous == exactly what one phase-2 block prefetches per step.

__global__ __launch_bounds__(256) void gemm_big(
        const unsigned short* __restrict__ xcat,
        const unsigned short* __restrict__ wbig,
        const float* __restrict__ bbig,
        unsigned short* __restrict__ ytile) {
    __shared__ __align__(16) unsigned short As[128][40];
    __shared__ __align__(16) unsigned short Bs[128][40];
    int nb = blockIdx.x;              // 0..23 (col block)
    int mb = blockIdx.y;              // 0..127 (row block)
    int tid = threadIdx.x;
    int lane = tid & 63, wid = tid >> 6;
    int wm = wid & 1, wn = wid >> 1;  // 2x2 wave grid, each wave 64x64
    int lm = lane & 15, lq = lane >> 4;
    v4f acc[4][4] = {};
    for (int kb = 0; kb < KCAT / 32; ++kb) {
        __syncthreads();
        #pragma unroll
        for (int it = 0; it < 2; ++it) {
            int cid = tid + it * 256;
            int r = cid >> 2, q = cid & 3;
            *(uint4*)&As[r][q * 8] =
                *(const uint4*)(xcat + (size_t)(mb * 128 + r) * KCAT + kb * 32 + q * 8);
            *(uint4*)&Bs[r][q * 8] =
                *(const uint4*)(wbig + (size_t)(nb * 128 + r) * KCAT + kb * 32 + q * 8);
        }
        __syncthreads();
        v8s a[4], b[4];
        #pragma unroll
        for (int i = 0; i < 4; ++i) a[i] = *(const v8s*)&As[wm * 64 + i * 16 + lm][lq * 8];
        #pragma unroll
        for (int j = 0; j < 4; ++j) b[j] = *(const v8s*)&Bs[wn * 64 + j * 16 + lm][lq * 8];
        #pragma unroll
        for (int i = 0; i < 4; ++i)
            #pragma unroll
            for (int j = 0; j < 4; ++j)
                acc[i][j] = __builtin_amdgcn_mfma_f32_16x16x32_bf16(a[i], b[j], acc[i][j], 0, 0, 0);
    }
    int tt = mb * 2 + wm;                     // time index of this wave's 64 rows
    #pragma unroll
    for (int i = 0; i < 4; ++i) {
        int rbase = i * 16 + lq * 4;          // batch row base (0..60)
        #pragma unroll
        for (int j = 0; j < 4; ++j) {
            int gn = nb * 128 + wn * 64 + j * 16 + lm;
            float bias = bbig[gn];
            bool do_tanh = (gn >= 2560);
            int slot, mcol;
            if (gn < 2048)      { slot = gn >> 9; mcol = gn & 511; }
            else if (gn < 2560) { slot = 4; mcol = gn - 2048; }
            else                { slot = 5; mcol = gn - 2560; }
            size_t base = ((((size_t)tt * NBLK2 + (mcol >> 4)) * 64 + rbase) * 6 + slot) * 16
                          + (mcol & 15);
            #pragma unroll
            for (int r = 0; r < 4; ++r) {
                float v = acc[i][j][r] + bias;
                if (do_tanh) v = tanhf(v);
                ytile[base + (size_t)r * 96] = f2bf(v);
            }
        }
    }
}

// ---------------- phase 2: persistent kernel, tag-embedded h exchange (1 hop/step) ----------------
// 32 blocks x 4 waves; block bk owns m-cols [16bk,16bk+16).
// No flags, no store-ack, no S0 barrier: each h word is (tag<<16)|bf16; producers
// fire-and-forget agent-scope u32 stores; each consumer wave polls exactly the 512B
// it feeds to MFMA until all tags == t. Per-word tags make store order irrelevant.
// WAR/deadlock safety (induction): a wave writes tag t+2 into buffer t&1 only after
// its poll saw tag t+1 from EVERY wave of EVERY block, which requires each of those
// waves to have finished consuming buffer t&1 (they publish t+1 only after their
// step-t poll+MFMA). Tags are unique per run (init: 0 / 0xFFFF poison).
// Epilogue is split over all 4 waves (wave (p,q) finishes tb=q); red exchange is
// symmetric; f32 a+b==b+a so results stay bit-identical.

__global__ __launch_bounds__(256, 1) void lstm_persist(
        const unsigned short* __restrict__ ytile,
        const unsigned short* __restrict__ w2,
        const float* __restrict__ b2,
        const float* __restrict__ c0,
        unsigned* hs0,
        unsigned* hs1,
        float* __restrict__ out) {
    __shared__ __align__(16) float red[2][2][5][256];            // 20 KB: K-partial exchange
    __shared__ __align__(16) unsigned short ybuf[3][6144];       // 36 KB: y slabs (triple buf)
    int bk = blockIdx.x;
    int tid = threadIdx.x;
    int lane = tid & 63, wid = tid >> 6;
    int p = wid >> 1;                 // batch half (MFMA rows p*32..p*32+32)
    int q = wid & 1;                  // K half for MFMA; tb slice for epilogue
    int lm = lane & 15, lq = lane >> 4;
    int m = bk * 16 + lm;

    // B fragments in registers: gate g, kk = q*8+j
    v8s bfrag[5][8];
    const unsigned short* w2b = w2 + (size_t)(bk * 80 + lm) * 512 + lq * 8;
    #pragma unroll
    for (int g = 0; g < 5; ++g)
        #pragma unroll
        for (int j = 0; j < 8; ++j)
            bfrag[g][j] = *(const v8s*)(w2b + (size_t)g * 16 * 512 + (q * 8 + j) * 32);

    float bias[5];
    #pragma unroll
    for (int g = 0; g < 5; ++g) bias[g] = b2[(bk * 5 + g) * 16 + lm];
    // c state for this wave's epilogue slice (rows p*32 + q*16 + lq*4 + r)
    float creg[4];
    #pragma unroll
    for (int r = 0; r < 4; ++r)
        creg[r] = c0[(p * 32 + q * 16 + lq * 4 + r) * 512 + m];

    // y prefetch: 12 chunks of 1KB per slab, wave wid takes chunks wid*3..wid*3+2
    auto prefetch = [&](int tt, int buf) {
        const unsigned short* slab = ytile + ((size_t)tt * NBLK2 + bk) * 6144;
        unsigned short* lbase = &ybuf[buf][0];
        #pragma unroll
        for (int i = 0; i < 3; ++i) {
            int ch = wid * 3 + i;
            __builtin_amdgcn_global_load_lds(
                (const __attribute__((address_space(1))) unsigned int*)(slab + ch * 512 + lane * 8),
                (__attribute__((address_space(3))) unsigned int*)(lbase + ch * 512), 16, 0, 0);
        }
    };
    prefetch(0, 0);
    prefetch(1, 1);

    for (int t = 0; t < T_STEPS; ++t) {
        const unsigned* hin = (t & 1) ? hs1 : hs0;
        unsigned*       hnx = (t & 1) ? hs0 : hs1;
        // (1) poll+load tagged h(t): per lane 2 rows x 8 j-groups x 32B = 64 u64
        u64 wv[64];
        {
            const u64* hb = (const u64*)hin + ((size_t)(p * 32 + lm)) * 256 + q * 128 + lq * 4;
            unsigned tg = (unsigned)t & 0xFFFFu;
            u64 ex = ((u64)tg << 16) | ((u64)tg << 48);
            while (true) {
                #pragma unroll
                for (int j = 0; j < 8; ++j)
                    #pragma unroll
                    for (int e = 0; e < 4; ++e) {
                        wv[j * 4 + e]      = __hip_atomic_load(hb + j * 16 + e,
                                                __ATOMIC_RELAXED, __HIP_MEMORY_SCOPE_AGENT);
                        wv[32 + j * 4 + e] = __hip_atomic_load(hb + 4096 + j * 16 + e,
                                                __ATOMIC_RELAXED, __HIP_MEMORY_SCOPE_AGENT);
                    }
                bool ok = true;
                #pragma unroll
                for (int i = 0; i < 64; ++i)
                    ok &= ((wv[i] & 0xFFFF0000FFFF0000ULL) == ex);
                if (__all(ok)) break;
            }
        }
        // (2) unpack tagged words -> bf16 fragments (v_perm: 1 op per output u32)
        v8s a0[8], a1[8];
        #pragma unroll
        for (int j = 0; j < 8; ++j) {
            union { unsigned u[4]; v8s v; } f0, f1;
            #pragma unroll
            for (int e = 0; e < 4; ++e) {
                u64 x0 = wv[j * 4 + e], x1 = wv[32 + j * 4 + e];
                f0.u[e] = __builtin_amdgcn_perm((unsigned)(x0 >> 32), (unsigned)x0, 0x05040100u);
                f1.u[e] = __builtin_amdgcn_perm((unsigned)(x1 >> 32), (unsigned)x1, 0x05040100u);
            }
            a0[j] = f0.v; a1[j] = f1.v;
        }
        // (3) MFMA chain (identical accumulation order to prior versions)
        v4f acc[2][5] = {};
        #pragma unroll
        for (int j = 0; j < 8; ++j) {
            #pragma unroll
            for (int g = 0; g < 5; ++g) {
                acc[0][g] = __builtin_amdgcn_mfma_f32_16x16x32_bf16(a0[j], bfrag[g][j], acc[0][g], 0, 0, 0);
                acc[1][g] = __builtin_amdgcn_mfma_f32_16x16x32_bf16(a1[j], bfrag[g][j], acc[1][g], 0, 0, 0);
            }
        }
        // (4) symmetric K-partial exchange: wave (p,q) gives away tb=q^1, keeps tb=q
        #pragma unroll
        for (int g = 0; g < 5; ++g)
            *(v4f*)&red[p][q ^ 1][g][lane * 4] = acc[q ^ 1][g];
        __syncthreads();                                   // S1 (only barrier per step)
        // (5) prefetch t+2 (post-S1: every wave has finished epilogue(t-1), so
        //     overwriting ybuf[(t+2)%3] == [(t-1)%3] is safe; drains at poll(t+1))
        if (t + 2 < T_STEPS) prefetch(t + 2, (t + 2) % 3);
        // (6) epilogue for this wave's 16 rows (tb = q)
        v4f fin[5];
        #pragma unroll
        for (int g = 0; g < 5; ++g)
            fin[g] = acc[q][g] + *(const v4f*)&red[p][q][g][lane * 4];
        const unsigned short* yb = &ybuf[t % 3][0];
        unsigned tagup = ((unsigned)(t + 1)) << 16;
        float hv[4];
        #pragma unroll
        for (int r = 0; r < 4; ++r) {
            int brow = p * 32 + q * 16 + lq * 4 + r;
            const unsigned short* ybr = yb + brow * 96;
            float f_ = sigmoid_fast(bf2f(ybr[0 * 16 + lm]) + fin[0][r] + bias[0]);
            float i_ = sigmoid_fast(bf2f(ybr[1 * 16 + lm]) + fin[1][r] + bias[1]);
            float o_ = sigmoid_fast(bf2f(ybr[2 * 16 + lm]) + fin[2][r] + bias[2]);
            float oc = sigmoid_fast(bf2f(ybr[3 * 16 + lm]) + fin[3][r] + bias[3]);
            float ct = tanh_fast  (bf2f(ybr[4 * 16 + lm]) + fin[4][r] + bias[4]);
            float wcs = bf2f(ybr[5 * 16 + lm]);
            float cn = i_ * ct + f_ * creg[r];
            creg[r] = cn;
            float hn = o_ * tanh_fast(cn) + oc * wcs;
            hv[r] = hn;
            // (7) fire-and-forget tagged publish — THE one hop
            __hip_atomic_store(hnx + (size_t)brow * 512 + m, tagup | (unsigned)f2bf(hn),
                               __ATOMIC_RELAXED, __HIP_MEMORY_SCOPE_AGENT);
        }
        // (8) out stores off the critical path
        #pragma unroll
        for (int r = 0; r < 4; ++r) {
            int brow = p * 32 + q * 16 + lq * 4 + r;
            out[((size_t)t * 64 + brow) * 512 + m] = hv[r];
            if (t == T_STEPS - 1)
                out[OUT_N + 32768 + (size_t)brow * 512 + m] = hv[r];   // h_fin
        }
    }

    // c_fin
    #pragma unroll
    for (int r = 0; r < 4; ++r)
        out[OUT_N + (size_t)(p * 32 + q * 16 + lq * 4 + r) * 512 + m] = creg[r];
}

// ---------------- launch ----------------

extern "C" void kernel_launch(void* const* d_in, const int* in_sizes, int n_in,
                              void* d_out, int out_size, void* d_ws, size_t ws_size,
                              hipStream_t stream) {
    const float* inputs = (const float*)d_in[0];
    const float* emb_s  = (const float*)d_in[1];
    const float* c0     = (const float*)d_in[2];
    const float* h0     = (const float*)d_in[3];
    const float* W_ioux = (const float*)d_in[4];  const float* b_ioux = (const float*)d_in[5];
    const float* W_iouh = (const float*)d_in[6];  const float* b_iouh = (const float*)d_in[7];
    const float* W_ious = (const float*)d_in[8];  const float* b_ious = (const float*)d_in[9];
    const float* W_fx   = (const float*)d_in[10]; const float* b_fx   = (const float*)d_in[11];
    const float* W_fh   = (const float*)d_in[12]; const float* b_fh   = (const float*)d_in[13];
    const float* W_wc   = (const float*)d_in[14]; const float* b_wc   = (const float*)d_in[15];
    float* out = (float*)d_out;

    char* ws = (char*)d_ws;
    size_t off = 0;
    auto alloc = [&](size_t bytes) -> void* {
        void* p = ws + off;
        off += (bytes + 255) & ~(size_t)255;
        return p;
    };
    unsigned short* ytile = (unsigned short*)alloc((size_t)NROWS * NBIG * 2);   // 100.7 MB
    unsigned short* xcat  = (unsigned short*)alloc((size_t)NROWS * KCAT * 2);   // 33.6 MB
    unsigned short* wbig  = (unsigned short*)alloc((size_t)NBIG * KCAT * 2);    // 6.3 MB
    float*          bbig  = (float*)alloc(NBIG * 4);
    unsigned short* w2    = (unsigned short*)alloc((size_t)W2ROWS * 512 * 2);   // 2.6 MB
    float*          b2    = (float*)alloc(W2ROWS * 4);
    unsigned*       hs0   = (unsigned*)alloc((size_t)B_DIM * MDIM * 4);         // 128 KB tagged
    unsigned*       hs1   = (unsigned*)alloc((size_t)B_DIM * MDIM * 4);         // 128 KB tagged

    pack_xcat<<<(NROWS * KCAT + 255) / 256, 256, 0, stream>>>(inputs, emb_s, xcat);
    pack_wbig<<<(NBIG * KCAT + 255) / 256, 256, 0, stream>>>(
        W_ioux, b_ioux, W_ious, b_ious, W_fx, b_fx, W_wc, b_wc, wbig, bbig);
    pack_w2<<<(W2ROWS * 512 + 255) / 256, 256, 0, stream>>>(W_iouh, b_iouh, W_fh, b_fh, w2, b2);
    init_state<<<(B_DIM * MDIM + 255) / 256, 256, 0, stream>>>(h0, hs0, hs1);

    dim3 g1(NBIG / 128, NROWS / 128);
    gemm_big<<<g1, 256, 0, stream>>>(xcat, wbig, bbig, ytile);

    lstm_persist<<<NBLK2, 256, 0, stream>>>(ytile, w2, b2, c0, hs0, hs1, out);
}

// Round 5
// 3351.350 us; speedup vs baseline: 1.1782x; 1.1782x over previous
//
#include <hip/hip_runtime.h>
#include <stdint.h>

#define T_STEPS 256
#define B_DIM   64
#define MDIM    512
#define NROWS   (T_STEPS * B_DIM)   // 16384
#define KCAT    1024                // [inputs | emb_s]
#define NBIG    3072                // 4M (iou) + M (ctx) + M (wcs)
#define W2ROWS  2560                // 5 gates * 512
#define NBLK2   32                  // persistent phase-2 blocks
#define OUT_N   ((size_t)T_STEPS * B_DIM * MDIM)  // 8388608

typedef short v8s __attribute__((ext_vector_type(8)));
typedef float v4f __attribute__((ext_vector_type(4)));
typedef unsigned long long u64;

static __device__ __forceinline__ unsigned short f2bf(float f) {
    unsigned u = __builtin_bit_cast(unsigned, f);
    u += 0x7FFFu + ((u >> 16) & 1u);            // RNE
    return (unsigned short)(u >> 16);
}
static __device__ __forceinline__ float bf2f(unsigned short h) {
    unsigned u = ((unsigned)h) << 16;
    return __builtin_bit_cast(float, u);
}
// fast transcendentals: v_rcp (~1ulp) + v_exp; rel err ~1e-6, far below the
// bf16 h-quantization noise (absmax 0.0195 vs threshold 0.0565)
static __device__ __forceinline__ float fast_rcp(float x) {
    return __builtin_amdgcn_rcpf(x);
}
static __device__ __forceinline__ float sigmoid_fast(float x) {
    return fast_rcp(1.0f + __expf(-x));
}
static __device__ __forceinline__ float tanh_fast(float x) {
    return 1.0f - 2.0f * fast_rcp(1.0f + __expf(2.0f * x));
}

// ---------------- prepack kernels ----------------

__global__ void pack_xcat(const float* __restrict__ x, const float* __restrict__ s,
                          unsigned short* __restrict__ xcat) {
    int idx = blockIdx.x * blockDim.x + threadIdx.x;   // over NROWS*KCAT
    if (idx >= NROWS * KCAT) return;
    int row = idx >> 10, col = idx & 1023;
    float v = (col < 512) ? x[row * 512 + col] : s[row * 512 + (col - 512)];
    xcat[idx] = f2bf(v);
}

__global__ void pack_wbig(const float* __restrict__ Wioux, const float* __restrict__ bioux,
                          const float* __restrict__ Wious, const float* __restrict__ bious,
                          const float* __restrict__ Wfx,   const float* __restrict__ bfx,
                          const float* __restrict__ Wwc,   const float* __restrict__ bwc,
                          unsigned short* __restrict__ wbig, float* __restrict__ bbig) {
    int idx = blockIdx.x * blockDim.x + threadIdx.x;   // over NBIG*KCAT
    if (idx >= NBIG * KCAT) return;
    int r = idx >> 10, c = idx & 1023;
    float v;
    if (r < 2048)      v = (c < 512) ? Wioux[r * 512 + c] : Wious[r * 512 + (c - 512)];
    else if (r < 2560) { int j = r - 2048; v = (c < 512) ? Wfx[j * 512 + c] : 0.0f; }
    else               { int j = r - 2560; v = (c < 512) ? 0.0f : Wwc[j * 512 + (c - 512)]; }
    wbig[idx] = f2bf(v);
    if (c == 0) {
        float b;
        if (r < 2048)      b = bioux[r] + bious[r];
        else if (r < 2560) b = bfx[r - 2048];
        else               b = bwc[r - 2560];
        bbig[r] = b;
    }
}

// Pack recurrent weights: block bk owns m-cols [16*bk,16*bk+16):
// 5 n-tiles of 16 rows: g=0..3 -> W_iouh rows g*512+m ; g=4 -> W_fh row m
__global__ void pack_w2(const float* __restrict__ Wiouh, const float* __restrict__ biouh,
                        const float* __restrict__ Wfh,   const float* __restrict__ bfh,
                        unsigned short* __restrict__ w2, float* __restrict__ b2) {
    int idx = blockIdx.x * blockDim.x + threadIdx.x;   // over W2ROWS*512
    if (idx >= W2ROWS * 512) return;
    int r = idx >> 9, k = idx & 511;
    int bk = r / 80, rem = r % 80, g = rem >> 4, j = rem & 15;
    int m = bk * 16 + j;
    float v, bias;
    if (g < 4) { v = Wiouh[(size_t)(g * 512 + m) * 512 + k]; bias = biouh[g * 512 + m]; }
    else       { v = Wfh[(size_t)m * 512 + k];               bias = bfh[m]; }
    w2[idx] = f2bf(v);
    if (k == 0) b2[r] = bias;
}

// Tagged h state: u32 word = (step_tag << 16) | bf16(h), row-major [64][512].
// buf0 = h(0) with tag 0; buf1 poisoned with tag 0xFFFF (never matches 1..256).
// flags: 128 producer-wave flags (fid = bk*4 + p*2 + q), each on its own 128B line.
__global__ void init_state(const float* __restrict__ h0,
                           unsigned* __restrict__ hs0,
                           unsigned* __restrict__ hs1,
                           int* __restrict__ flags) {
    int idx = blockIdx.x * blockDim.x + threadIdx.x;   // 32768
    if (idx < 128 * 32) flags[idx] = 0;
    if (idx >= B_DIM * MDIM) return;
    hs0[idx] = (unsigned)f2bf(h0[idx]);                // tag 0 in hi16
    hs1[idx] = 0xFFFF0000u;
}

// ---------------- phase 1: big GEMM, output pre-swizzled into per-(t,block) slabs ----------------
// ytile layout: [T][32 bk][64 b][6 slot][16 col] bf16 ; slot 0..3 = iou gates, 4 = ctx, 5 = wcs(tanh).
// Each (t,bk) slab is 12 KB contiguous == exactly what one phase-2 block prefetches per step.

__global__ __launch_bounds__(256) void gemm_big(
        const unsigned short* __restrict__ xcat,
        const unsigned short* __restrict__ wbig,
        const float* __restrict__ bbig,
        unsigned short* __restrict__ ytile) {
    __shared__ __align__(16) unsigned short As[128][40];
    __shared__ __align__(16) unsigned short Bs[128][40];
    int nb = blockIdx.x;              // 0..23 (col block)
    int mb = blockIdx.y;              // 0..127 (row block)
    int tid = threadIdx.x;
    int lane = tid & 63, wid = tid >> 6;
    int wm = wid & 1, wn = wid >> 1;  // 2x2 wave grid, each wave 64x64
    int lm = lane & 15, lq = lane >> 4;
    v4f acc[4][4] = {};
    for (int kb = 0; kb < KCAT / 32; ++kb) {
        __syncthreads();
        #pragma unroll
        for (int it = 0; it < 2; ++it) {
            int cid = tid + it * 256;
            int r = cid >> 2, q = cid & 3;
            *(uint4*)&As[r][q * 8] =
                *(const uint4*)(xcat + (size_t)(mb * 128 + r) * KCAT + kb * 32 + q * 8);
            *(uint4*)&Bs[r][q * 8] =
                *(const uint4*)(wbig + (size_t)(nb * 128 + r) * KCAT + kb * 32 + q * 8);
        }
        __syncthreads();
        v8s a[4], b[4];
        #pragma unroll
        for (int i = 0; i < 4; ++i) a[i] = *(const v8s*)&As[wm * 64 + i * 16 + lm][lq * 8];
        #pragma unroll
        for (int j = 0; j < 4; ++j) b[j] = *(const v8s*)&Bs[wn * 64 + j * 16 + lm][lq * 8];
        #pragma unroll
        for (int i = 0; i < 4; ++i)
            #pragma unroll
            for (int j = 0; j < 4; ++j)
                acc[i][j] = __builtin_amdgcn_mfma_f32_16x16x32_bf16(a[i], b[j], acc[i][j], 0, 0, 0);
    }
    int tt = mb * 2 + wm;                     // time index of this wave's 64 rows
    #pragma unroll
    for (int i = 0; i < 4; ++i) {
        int rbase = i * 16 + lq * 4;          // batch row base (0..60)
        #pragma unroll
        for (int j = 0; j < 4; ++j) {
            int gn = nb * 128 + wn * 64 + j * 16 + lm;
            float bias = bbig[gn];
            bool do_tanh = (gn >= 2560);
            int slot, mcol;
            if (gn < 2048)      { slot = gn >> 9; mcol = gn & 511; }
            else if (gn < 2560) { slot = 4; mcol = gn - 2048; }
            else                { slot = 5; mcol = gn - 2560; }
            size_t base = ((((size_t)tt * NBLK2 + (mcol >> 4)) * 64 + rbase) * 6 + slot) * 16
                          + (mcol & 15);
            #pragma unroll
            for (int r = 0; r < 4; ++r) {
                float v = acc[i][j][r] + bias;
                if (do_tanh) v = tanhf(v);
                ytile[base + (size_t)r * 96] = f2bf(v);
            }
        }
    }
}

// ---------------- phase 2: persistent kernel, tagged data + flag-hint sync ----------------
// 32 blocks x 4 waves; block bk owns m-cols [16bk,16bk+16); wave (p,q):
//   MFMA rows p*32..p*32+31, K-half q; epilogue rows p*32+q*16..+16.
// Producer (end of step t): 4 fire-and-forget tagged u32 h stores (tag t+1), then
// flag[fid]=t+1 (NO vmcnt ack — flag is a HINT). Consumer (step t): polls the 32
// flags covering its operand (1 load/lane), then ONE staged data load with tag
// verification (retry covers flag-outran-data). v4 lesson: poll object must be
// tiny; v3 lesson: spread flag lines.
// WAR induction: wave publishes tag t+1 only after its MFMA consumed all tag-t
// words; so when any wave writes buffer (t+1)&1, all readers of that buffer's
// t-1 generation have retired their loads. Tags unique (init 0 / 0xFFFF poison).

__global__ __launch_bounds__(256, 1) void lstm_persist(
        const unsigned short* __restrict__ ytile,
        const unsigned short* __restrict__ w2,
        const float* __restrict__ b2,
        const float* __restrict__ c0,
        unsigned* hs0,
        unsigned* hs1,
        float* __restrict__ out,
        int* __restrict__ flags) {
    __shared__ __align__(16) float red[2][2][5][256];            // 20 KB: K-partial exchange
    __shared__ __align__(16) unsigned short ybuf[3][6144];       // 36 KB: y slabs (triple buf)
    int bk = blockIdx.x;
    int tid = threadIdx.x;
    int lane = tid & 63, wid = tid >> 6;
    int p = wid >> 1;                 // batch half (MFMA rows p*32..p*32+32)
    int q = wid & 1;                  // K half for MFMA; tb slice for epilogue
    int lm = lane & 15, lq = lane >> 4;
    int m = bk * 16 + lm;

    // B fragments in registers: gate g, kk = q*8+j
    v8s bfrag[5][8];
    const unsigned short* w2b = w2 + (size_t)(bk * 80 + lm) * 512 + lq * 8;
    #pragma unroll
    for (int g = 0; g < 5; ++g)
        #pragma unroll
        for (int j = 0; j < 8; ++j)
            bfrag[g][j] = *(const v8s*)(w2b + (size_t)g * 16 * 512 + (q * 8 + j) * 32);

    float bias[5];
    #pragma unroll
    for (int g = 0; g < 5; ++g) bias[g] = b2[(bk * 5 + g) * 16 + lm];
    // c state for this wave's epilogue slice (rows p*32 + q*16 + lq*4 + r)
    float creg[4];
    #pragma unroll
    for (int r = 0; r < 4; ++r)
        creg[r] = c0[(p * 32 + q * 16 + lq * 4 + r) * 512 + m];

    // poll set: this wave's operand = rows p*32..+31, cols [q*256, q*256+256)
    // -> producers: blocks q*16..q*16+15, waves (p,0),(p,1). fid = bk*4 + p*2 + qq.
    int jj = lane & 31;
    int fpoll = ((q * 16 + (jj >> 1)) * 4 + p * 2 + (jj & 1)) * 32;
    int fid_self = (bk * 4 + p * 2 + q) * 32;

    // y prefetch: 12 chunks of 1KB per slab, wave wid takes chunks wid*3..wid*3+2
    auto prefetch = [&](int tt, int buf) {
        const unsigned short* slab = ytile + ((size_t)tt * NBLK2 + bk) * 6144;
        unsigned short* lbase = &ybuf[buf][0];
        #pragma unroll
        for (int i = 0; i < 3; ++i) {
            int ch = wid * 3 + i;
            __builtin_amdgcn_global_load_lds(
                (const __attribute__((address_space(1))) unsigned int*)(slab + ch * 512 + lane * 8),
                (__attribute__((address_space(3))) unsigned int*)(lbase + ch * 512), 16, 0, 0);
        }
    };
    prefetch(0, 0);
    prefetch(1, 1);

    for (int t = 0; t < T_STEPS; ++t) {
        const unsigned* hin = (t & 1) ? hs1 : hs0;
        unsigned*       hnx = (t & 1) ? hs0 : hs1;
        // (1) cheap poll: 1 flag load per lane until all producers have ISSUED h(t)
        if (t) {
            while (!__all(__hip_atomic_load(flags + fpoll, __ATOMIC_RELAXED,
                                            __HIP_MEMORY_SCOPE_AGENT) >= t)) {}
            asm volatile("" ::: "memory");
        }
        // (2) staged tagged data load + verify (one RTT in the common case)
        const u64* hb = (const u64*)hin + ((size_t)(p * 32 + lm)) * 256 + q * 128 + lq * 4;
        unsigned tg = (unsigned)t & 0xFFFFu;
        u64 ex = ((u64)tg << 16) | ((u64)tg << 48);
        v8s a0[8], a1[8];
        #pragma unroll
        for (int half = 0; half < 2; ++half) {
            const u64* hh = hb + half * 4096;          // +16 rows
            u64 wv[32];
            while (true) {
                #pragma unroll
                for (int j = 0; j < 8; ++j)
                    #pragma unroll
                    for (int e = 0; e < 4; ++e)
                        wv[j * 4 + e] = __hip_atomic_load(hh + j * 16 + e,
                                            __ATOMIC_RELAXED, __HIP_MEMORY_SCOPE_AGENT);
                bool ok = true;
                #pragma unroll
                for (int i = 0; i < 32; ++i)
                    ok &= ((wv[i] & 0xFFFF0000FFFF0000ULL) == ex);
                if (__all(ok)) break;
            }
            #pragma unroll
            for (int j = 0; j < 8; ++j) {
                union { unsigned u[4]; v8s v; } f;
                #pragma unroll
                for (int e = 0; e < 4; ++e) {
                    u64 x = wv[j * 4 + e];
                    f.u[e] = __builtin_amdgcn_perm((unsigned)(x >> 32), (unsigned)x, 0x05040100u);
                }
                if (half == 0) a0[j] = f.v; else a1[j] = f.v;
            }
        }
        // (3) MFMA chain (identical accumulation order to prior versions)
        v4f acc[2][5] = {};
        #pragma unroll
        for (int j = 0; j < 8; ++j) {
            #pragma unroll
            for (int g = 0; g < 5; ++g) {
                acc[0][g] = __builtin_amdgcn_mfma_f32_16x16x32_bf16(a0[j], bfrag[g][j], acc[0][g], 0, 0, 0);
                acc[1][g] = __builtin_amdgcn_mfma_f32_16x16x32_bf16(a1[j], bfrag[g][j], acc[1][g], 0, 0, 0);
            }
        }
        // (4) symmetric K-partial exchange: wave (p,q) gives away tb=q^1, keeps tb=q
        #pragma unroll
        for (int g = 0; g < 5; ++g)
            *(v4f*)&red[p][q ^ 1][g][lane * 4] = acc[q ^ 1][g];
        __syncthreads();                                   // S1 (only barrier per step)
        // (5) prefetch t+2 (post-S1; drained by S1(t+1)'s implicit vmcnt(0))
        if (t + 2 < T_STEPS) prefetch(t + 2, (t + 2) % 3);
        // (6) epilogue for this wave's 16 rows (tb = q), publish-as-computed
        v4f fin[5];
        #pragma unroll
        for (int g = 0; g < 5; ++g)
            fin[g] = acc[q][g] + *(const v4f*)&red[p][q][g][lane * 4];
        const unsigned short* yb = &ybuf[t % 3][0];
        unsigned tagup = ((unsigned)(t + 1)) << 16;
        float hv[4];
        #pragma unroll
        for (int r = 0; r < 4; ++r) {
            int brow = p * 32 + q * 16 + lq * 4 + r;
            const unsigned short* ybr = yb + brow * 96;
            float f_ = sigmoid_fast(bf2f(ybr[0 * 16 + lm]) + fin[0][r] + bias[0]);
            float i_ = sigmoid_fast(bf2f(ybr[1 * 16 + lm]) + fin[1][r] + bias[1]);
            float o_ = sigmoid_fast(bf2f(ybr[2 * 16 + lm]) + fin[2][r] + bias[2]);
            float oc = sigmoid_fast(bf2f(ybr[3 * 16 + lm]) + fin[3][r] + bias[3]);
            float ct = tanh_fast  (bf2f(ybr[4 * 16 + lm]) + fin[4][r] + bias[4]);
            float wcs = bf2f(ybr[5 * 16 + lm]);
            float cn = i_ * ct + f_ * creg[r];
            creg[r] = cn;
            float hn = o_ * tanh_fast(cn) + oc * wcs;
            hv[r] = hn;
            __hip_atomic_store(hnx + (size_t)brow * 512 + m, tagup | (unsigned)f2bf(hn),
                               __ATOMIC_RELAXED, __HIP_MEMORY_SCOPE_AGENT);
        }
        // (7) flag hint: fire-and-forget, NO ack (tag-verify carries correctness)
        if (lane == 0 && t + 1 < T_STEPS)
            __hip_atomic_store(flags + fid_self, t + 1,
                               __ATOMIC_RELAXED, __HIP_MEMORY_SCOPE_AGENT);
        // (8) out stores off the critical path
        #pragma unroll
        for (int r = 0; r < 4; ++r) {
            int brow = p * 32 + q * 16 + lq * 4 + r;
            out[((size_t)t * 64 + brow) * 512 + m] = hv[r];
            if (t == T_STEPS - 1)
                out[OUT_N + 32768 + (size_t)brow * 512 + m] = hv[r];   // h_fin
        }
    }

    // c_fin
    #pragma unroll
    for (int r = 0; r < 4; ++r)
        out[OUT_N + (size_t)(p * 32 + q * 16 + lq * 4 + r) * 512 + m] = creg[r];
}

// ---------------- launch ----------------

extern "C" void kernel_launch(void* const* d_in, const int* in_sizes, int n_in,
                              void* d_out, int out_size, void* d_ws, size_t ws_size,
                              hipStream_t stream) {
    const float* inputs = (const float*)d_in[0];
    const float* emb_s  = (const float*)d_in[1];
    const float* c0     = (const float*)d_in[2];
    const float* h0     = (const float*)d_in[3];
    const float* W_ioux = (const float*)d_in[4];  const float* b_ioux = (const float*)d_in[5];
    const float* W_iouh = (const float*)d_in[6];  const float* b_iouh = (const float*)d_in[7];
    const float* W_ious = (const float*)d_in[8];  const float* b_ious = (const float*)d_in[9];
    const float* W_fx   = (const float*)d_in[10]; const float* b_fx   = (const float*)d_in[11];
    const float* W_fh   = (const float*)d_in[12]; const float* b_fh   = (const float*)d_in[13];
    const float* W_wc   = (const float*)d_in[14]; const float* b_wc   = (const float*)d_in[15];
    float* out = (float*)d_out;

    char* ws = (char*)d_ws;
    size_t off = 0;
    auto alloc = [&](size_t bytes) -> void* {
        void* p = ws + off;
        off += (bytes + 255) & ~(size_t)255;
        return p;
    };
    unsigned short* ytile = (unsigned short*)alloc((size_t)NROWS * NBIG * 2);   // 100.7 MB
    unsigned short* xcat  = (unsigned short*)alloc((size_t)NROWS * KCAT * 2);   // 33.6 MB
    unsigned short* wbig  = (unsigned short*)alloc((size_t)NBIG * KCAT * 2);    // 6.3 MB
    float*          bbig  = (float*)alloc(NBIG * 4);
    unsigned short* w2    = (unsigned short*)alloc((size_t)W2ROWS * 512 * 2);   // 2.6 MB
    float*          b2    = (float*)alloc(W2ROWS * 4);
    unsigned*       hs0   = (unsigned*)alloc((size_t)B_DIM * MDIM * 4);         // 128 KB tagged
    unsigned*       hs1   = (unsigned*)alloc((size_t)B_DIM * MDIM * 4);         // 128 KB tagged
    int*            flags = (int*)alloc(128 * 32 * 4);                          // 16 KB

    pack_xcat<<<(NROWS * KCAT + 255) / 256, 256, 0, stream>>>(inputs, emb_s, xcat);
    pack_wbig<<<(NBIG * KCAT + 255) / 256, 256, 0, stream>>>(
        W_ioux, b_ioux, W_ious, b_ious, W_fx, b_fx, W_wc, b_wc, wbig, bbig);
    pack_w2<<<(W2ROWS * 512 + 255) / 256, 256, 0, stream>>>(W_iouh, b_iouh, W_fh, b_fh, w2, b2);
    init_state<<<(B_DIM * MDIM + 255) / 256, 256, 0, stream>>>(h0, hs0, hs1, flags);

    dim3 g1(NBIG / 128, NROWS / 128);
    gemm_big<<<g1, 256, 0, stream>>>(xcat, wbig, bbig, ytile);

    lstm_persist<<<NBLK2, 256, 0, stream>>>(ytile, w2, b2, c0, hs0, hs1, out, flags);
}

// Round 6
// 2398.156 us; speedup vs baseline: 1.6464x; 1.3975x over previous
//
#include <hip/hip_runtime.h>
#include <stdint.h>

#define T_STEPS 256
#define B_DIM   64
#define MDIM    512
#define NROWS   (T_STEPS * B_DIM)   // 16384
#define KCAT    1024                // [inputs | emb_s]
#define NBIG    3072                // 4M (iou) + M (ctx) + M (wcs)
#define W2ROWS  2560                // 5 gates * 512
#define NBLK2   32                  // persistent phase-2 blocks
#define OUT_N   ((size_t)T_STEPS * B_DIM * MDIM)  // 8388608

typedef short v8s __attribute__((ext_vector_type(8)));
typedef float v4f __attribute__((ext_vector_type(4)));
typedef unsigned long long u64;

static __device__ __forceinline__ unsigned short f2bf(float f) {
    unsigned u = __builtin_bit_cast(unsigned, f);
    u += 0x7FFFu + ((u >> 16) & 1u);            // RNE
    return (unsigned short)(u >> 16);
}
static __device__ __forceinline__ float bf2f(unsigned short h) {
    unsigned u = ((unsigned)h) << 16;
    return __builtin_bit_cast(float, u);
}
// fast transcendentals: v_rcp (~1ulp) + v_exp; rel err ~1e-6, far below the
// bf16 h-quantization noise (absmax 0.0195 vs threshold 0.0565)
static __device__ __forceinline__ float fast_rcp(float x) {
    return __builtin_amdgcn_rcpf(x);
}
static __device__ __forceinline__ float sigmoid_fast(float x) {
    return fast_rcp(1.0f + __expf(-x));
}
static __device__ __forceinline__ float tanh_fast(float x) {
    return 1.0f - 2.0f * fast_rcp(1.0f + __expf(2.0f * x));
}

// ---------------- prepack kernels ----------------

__global__ void pack_xcat(const float* __restrict__ x, const float* __restrict__ s,
                          unsigned short* __restrict__ xcat) {
    int idx = blockIdx.x * blockDim.x + threadIdx.x;   // over NROWS*KCAT
    if (idx >= NROWS * KCAT) return;
    int row = idx >> 10, col = idx & 1023;
    float v = (col < 512) ? x[row * 512 + col] : s[row * 512 + (col - 512)];
    xcat[idx] = f2bf(v);
}

__global__ void pack_wbig(const float* __restrict__ Wioux, const float* __restrict__ bioux,
                          const float* __restrict__ Wious, const float* __restrict__ bious,
                          const float* __restrict__ Wfx,   const float* __restrict__ bfx,
                          const float* __restrict__ Wwc,   const float* __restrict__ bwc,
                          unsigned short* __restrict__ wbig, float* __restrict__ bbig) {
    int idx = blockIdx.x * blockDim.x + threadIdx.x;   // over NBIG*KCAT
    if (idx >= NBIG * KCAT) return;
    int r = idx >> 10, c = idx & 1023;
    float v;
    if (r < 2048)      v = (c < 512) ? Wioux[r * 512 + c] : Wious[r * 512 + (c - 512)];
    else if (r < 2560) { int j = r - 2048; v = (c < 512) ? Wfx[j * 512 + c] : 0.0f; }
    else               { int j = r - 2560; v = (c < 512) ? 0.0f : Wwc[j * 512 + (c - 512)]; }
    wbig[idx] = f2bf(v);
    if (c == 0) {
        float b;
        if (r < 2048)      b = bioux[r] + bious[r];
        else if (r < 2560) b = bfx[r - 2048];
        else               b = bwc[r - 2560];
        bbig[r] = b;
    }
}

// Pack recurrent weights: block bk owns m-cols [16*bk,16*bk+16):
// 5 n-tiles of 16 rows: g=0..3 -> W_iouh rows g*512+m ; g=4 -> W_fh row m
__global__ void pack_w2(const float* __restrict__ Wiouh, const float* __restrict__ biouh,
                        const float* __restrict__ Wfh,   const float* __restrict__ bfh,
                        unsigned short* __restrict__ w2, float* __restrict__ b2) {
    int idx = blockIdx.x * blockDim.x + threadIdx.x;   // over W2ROWS*512
    if (idx >= W2ROWS * 512) return;
    int r = idx >> 9, k = idx & 511;
    int bk = r / 80, rem = r % 80, g = rem >> 4, j = rem & 15;
    int m = bk * 16 + j;
    float v, bias;
    if (g < 4) { v = Wiouh[(size_t)(g * 512 + m) * 512 + k]; bias = biouh[g * 512 + m]; }
    else       { v = Wfh[(size_t)m * 512 + k];               bias = bfh[m]; }
    w2[idx] = f2bf(v);
    if (k == 0) b2[r] = bias;
}

// h state layout: [slice = col>>4][64 rows][16 cols] bf16 so each phase-2 block's
// slice (its 16 m-cols) is one contiguous 2 KB slab.
// flags: 128 producer-wave flags (fid = bk*4 + wid), each on its OWN 128B line.
__global__ void init_state(const float* __restrict__ h0,
                           unsigned short* __restrict__ hslab0,
                           int* __restrict__ flags) {
    int idx = blockIdx.x * blockDim.x + threadIdx.x;   // 32768
    if (idx < 128 * 32) flags[idx] = 0;
    if (idx >= B_DIM * MDIM) return;
    int row = idx >> 9, col = idx & 511;
    hslab0[((col >> 4) * 64 + row) * 16 + (col & 15)] = f2bf(h0[idx]);
}

// ---------------- phase 1: big GEMM, output pre-swizzled into per-(t,block) slabs ----------------
// ytile layout: [T][32 bk][64 b][6 slot][16 col] bf16 ; slot 0..3 = iou gates, 4 = ctx, 5 = wcs(tanh).
// Each (t,bk) slab is 12 KB contiguous == exactly what one phase-2 block prefetches per step.

__global__ __launch_bounds__(256) void gemm_big(
        const unsigned short* __restrict__ xcat,
        const unsigned short* __restrict__ wbig,
        const float* __restrict__ bbig,
        unsigned short* __restrict__ ytile) {
    __shared__ __align__(16) unsigned short As[128][40];
    __shared__ __align__(16) unsigned short Bs[128][40];
    int nb = blockIdx.x;              // 0..23 (col block)
    int mb = blockIdx.y;              // 0..127 (row block)
    int tid = threadIdx.x;
    int lane = tid & 63, wid = tid >> 6;
    int wm = wid & 1, wn = wid >> 1;  // 2x2 wave grid, each wave 64x64
    int lm = lane & 15, lq = lane >> 4;
    v4f acc[4][4] = {};
    for (int kb = 0; kb < KCAT / 32; ++kb) {
        __syncthreads();
        #pragma unroll
        for (int it = 0; it < 2; ++it) {
            int cid = tid + it * 256;
            int r = cid >> 2, q = cid & 3;
            *(uint4*)&As[r][q * 8] =
                *(const uint4*)(xcat + (size_t)(mb * 128 + r) * KCAT + kb * 32 + q * 8);
            *(uint4*)&Bs[r][q * 8] =
                *(const uint4*)(wbig + (size_t)(nb * 128 + r) * KCAT + kb * 32 + q * 8);
        }
        __syncthreads();
        v8s a[4], b[4];
        #pragma unroll
        for (int i = 0; i < 4; ++i) a[i] = *(const v8s*)&As[wm * 64 + i * 16 + lm][lq * 8];
        #pragma unroll
        for (int j = 0; j < 4; ++j) b[j] = *(const v8s*)&Bs[wn * 64 + j * 16 + lm][lq * 8];
        #pragma unroll
        for (int i = 0; i < 4; ++i)
            #pragma unroll
            for (int j = 0; j < 4; ++j)
                acc[i][j] = __builtin_amdgcn_mfma_f32_16x16x32_bf16(a[i], b[j], acc[i][j], 0, 0, 0);
    }
    int tt = mb * 2 + wm;                     // time index of this wave's 64 rows
    #pragma unroll
    for (int i = 0; i < 4; ++i) {
        int rbase = i * 16 + lq * 4;          // batch row base (0..60)
        #pragma unroll
        for (int j = 0; j < 4; ++j) {
            int gn = nb * 128 + wn * 64 + j * 16 + lm;
            float bias = bbig[gn];
            bool do_tanh = (gn >= 2560);
            int slot, mcol;
            if (gn < 2048)      { slot = gn >> 9; mcol = gn & 511; }
            else if (gn < 2560) { slot = 4; mcol = gn - 2048; }
            else                { slot = 5; mcol = gn - 2560; }
            size_t base = ((((size_t)tt * NBLK2 + (mcol >> 4)) * 64 + rbase) * 6 + slot) * 16
                          + (mcol & 15);
            #pragma unroll
            for (int r = 0; r < 4; ++r) {
                float v = acc[i][j][r] + bias;
                if (do_tanh) v = tanhf(v);
                ytile[base + (size_t)r * 96] = f2bf(v);
            }
        }
    }
}

// ---------------- phase 2: persistent kernel (v3 protocol + latency trims) ----------------
// 32 blocks x 4 waves; block bk owns m-cols [16bk,16bk+16); wave (p,q):
//   MFMA rows p*32..p*32+31 over K-half q; epilogue slice tb=q (rows p*32+q*16..+16).
// Per step: each wave polls ALL 128 flags (2 loads/lane, spread 128B lines; global
// poll set preserves v3's WAR induction, no S0 barrier) -> coherent h loads -> MFMA
// -> symmetric red exchange -> S1 -> 1/4 epilogue with publish-as-computed sc1
// stores -> vmcnt(0) ack (4 stores only) -> own flag -> out stores -> prefetch t+2.
// WAR safety: identical to v3 — flag(t+1) set after this wave's h(t) loads retired
// (MFMA consumed them before epilogue); a wave writes buffer (t+1)&1 only after its
// poll saw t from every producer wave, i.e. all readers of that buffer's t-1
// generation are done.

__global__ __launch_bounds__(256, 1) void lstm_persist(
        const unsigned short* __restrict__ ytile,
        const unsigned short* __restrict__ w2,
        const float* __restrict__ b2,
        const float* __restrict__ c0,
        unsigned short* hbuf0,
        unsigned short* hbuf1,
        float* __restrict__ out,
        int* __restrict__ flags) {
    __shared__ __align__(16) float red[2][2][5][256];            // 20 KB: K-partial exchange
    __shared__ __align__(16) unsigned short ybuf[3][6144];       // 36 KB: y slabs (triple buf)
    int bk = blockIdx.x;
    int tid = threadIdx.x;
    int lane = tid & 63, wid = tid >> 6;
    int p = wid >> 1;                 // batch half (MFMA rows p*32..p*32+32)
    int q = wid & 1;                  // K half for MFMA; tb slice for epilogue
    int lm = lane & 15, lq = lane >> 4;
    int m = bk * 16 + lm;

    // B fragments in registers: gate g, kk = q*8+j
    v8s bfrag[5][8];
    const unsigned short* w2b = w2 + (size_t)(bk * 80 + lm) * 512 + lq * 8;
    #pragma unroll
    for (int g = 0; g < 5; ++g)
        #pragma unroll
        for (int j = 0; j < 8; ++j)
            bfrag[g][j] = *(const v8s*)(w2b + (size_t)g * 16 * 512 + (q * 8 + j) * 32);

    float bias[5];
    #pragma unroll
    for (int g = 0; g < 5; ++g) bias[g] = b2[(bk * 5 + g) * 16 + lm];
    // c state for this wave's epilogue slice (rows p*32 + q*16 + lq*4 + r)
    float creg[4];
    #pragma unroll
    for (int r = 0; r < 4; ++r)
        creg[r] = c0[(p * 32 + q * 16 + lq * 4 + r) * 512 + m];

    int fid_self = (bk * 4 + wid) * 32;

    // y prefetch: 12 chunks of 1KB per slab, wave wid takes chunks wid*3..wid*3+2
    auto prefetch = [&](int tt, int buf) {
        const unsigned short* slab = ytile + ((size_t)tt * NBLK2 + bk) * 6144;
        unsigned short* lbase = &ybuf[buf][0];
        #pragma unroll
        for (int i = 0; i < 3; ++i) {
            int ch = wid * 3 + i;
            __builtin_amdgcn_global_load_lds(
                (const __attribute__((address_space(1))) unsigned int*)(slab + ch * 512 + lane * 8),
                (__attribute__((address_space(3))) unsigned int*)(lbase + ch * 512), 16, 0, 0);
        }
    };
    prefetch(0, 0);
    prefetch(1, 1);

    for (int t = 0; t < T_STEPS; ++t) {
        const unsigned short* hin = (t & 1) ? hbuf1 : hbuf0;
        unsigned*             hnx = (unsigned*)((t & 1) ? hbuf0 : hbuf1);
        // (1) every wave polls ALL 128 flags: 2 loads/lane over spread lines
        if (t) {
            while (true) {
                int f0 = __hip_atomic_load(flags + lane * 32, __ATOMIC_RELAXED,
                                           __HIP_MEMORY_SCOPE_AGENT);
                int f1 = __hip_atomic_load(flags + (64 + lane) * 32, __ATOMIC_RELAXED,
                                           __HIP_MEMORY_SCOPE_AGENT);
                if (__all(f0 >= t && f1 >= t)) break;
            }
            asm volatile("" ::: "memory");
        }
        // (2) batched coherent h loads (v3-proven layout & pattern)
        u64 hq[32];
        {
            const u64* hb = (const u64*)hin + ((size_t)(q * 16 + (lq >> 1)) * 64 + p * 32 + lm) * 4
                          + (lq & 1) * 2;
            #pragma unroll
            for (int j = 0; j < 8; ++j) {
                hq[j * 4 + 0] = __hip_atomic_load(hb + j * 512,      __ATOMIC_RELAXED, __HIP_MEMORY_SCOPE_AGENT);
                hq[j * 4 + 1] = __hip_atomic_load(hb + j * 512 + 1,  __ATOMIC_RELAXED, __HIP_MEMORY_SCOPE_AGENT);
                hq[j * 4 + 2] = __hip_atomic_load(hb + j * 512 + 64, __ATOMIC_RELAXED, __HIP_MEMORY_SCOPE_AGENT);
                hq[j * 4 + 3] = __hip_atomic_load(hb + j * 512 + 65, __ATOMIC_RELAXED, __HIP_MEMORY_SCOPE_AGENT);
            }
        }
        // (3) MFMA chain (identical accumulation order)
        v4f acc[2][5] = {};
        #pragma unroll
        for (int j = 0; j < 8; ++j) {
            union { u64 qq[2]; v8s v; } a0, a1;
            a0.qq[0] = hq[j * 4 + 0]; a0.qq[1] = hq[j * 4 + 1];
            a1.qq[0] = hq[j * 4 + 2]; a1.qq[1] = hq[j * 4 + 3];
            #pragma unroll
            for (int g = 0; g < 5; ++g) {
                acc[0][g] = __builtin_amdgcn_mfma_f32_16x16x32_bf16(a0.v, bfrag[g][j], acc[0][g], 0, 0, 0);
                acc[1][g] = __builtin_amdgcn_mfma_f32_16x16x32_bf16(a1.v, bfrag[g][j], acc[1][g], 0, 0, 0);
            }
        }
        // (4) symmetric K-partial exchange: wave (p,q) gives away tb=q^1, keeps tb=q
        #pragma unroll
        for (int g = 0; g < 5; ++g)
            *(v4f*)&red[p][q ^ 1][g][lane * 4] = acc[q ^ 1][g];
        __syncthreads();                                   // S1 (only barrier per step)
        // (5) reduce + 1/4 epilogue, publish-as-computed
        v4f fin[5];
        #pragma unroll
        for (int g = 0; g < 5; ++g)
            fin[g] = acc[q][g] + *(const v4f*)&red[p][q][g][lane * 4];
        const unsigned short* yb = &ybuf[t % 3][0];
        float hv[4];
        #pragma unroll
        for (int r = 0; r < 4; ++r) {
            int brow = p * 32 + q * 16 + lq * 4 + r;
            const unsigned short* ybr = yb + brow * 96;
            float f_ = sigmoid_fast(bf2f(ybr[0 * 16 + lm]) + fin[0][r] + bias[0]);
            float i_ = sigmoid_fast(bf2f(ybr[1 * 16 + lm]) + fin[1][r] + bias[1]);
            float o_ = sigmoid_fast(bf2f(ybr[2 * 16 + lm]) + fin[2][r] + bias[2]);
            float oc = sigmoid_fast(bf2f(ybr[3 * 16 + lm]) + fin[3][r] + bias[3]);
            float ct = tanh_fast  (bf2f(ybr[4 * 16 + lm]) + fin[4][r] + bias[4]);
            float wcs = bf2f(ybr[5 * 16 + lm]);
            float cn = i_ * ct + f_ * creg[r];
            creg[r] = cn;
            float hn = o_ * tanh_fast(cn) + oc * wcs;
            hv[r] = hn;
            // publish immediately: pair adjacent cols via shfl, even-lm lanes store u32
            unsigned hb16 = (unsigned)f2bf(hn);
            unsigned other = (unsigned)__shfl_xor((int)hb16, 1);
            if ((lm & 1) == 0) {
                unsigned w = (hb16 & 0xFFFFu) | (other << 16);
                __hip_atomic_store(hnx + (size_t)(bk * 64 + brow) * 8 + (lm >> 1), w,
                                   __ATOMIC_RELAXED, __HIP_MEMORY_SCOPE_AGENT);
            }
        }
        // (6) ack ONLY the 4 h stores (prefetch/out of prior steps already drained), flag
        asm volatile("s_waitcnt vmcnt(0)" ::: "memory");
        if (lane == 0 && t + 1 < T_STEPS)
            __hip_atomic_store(flags + fid_self, t + 1,
                               __ATOMIC_RELAXED, __HIP_MEMORY_SCOPE_AGENT);
        // (7) out stores off the critical path
        #pragma unroll
        for (int r = 0; r < 4; ++r) {
            int brow = p * 32 + q * 16 + lq * 4 + r;
            out[((size_t)t * 64 + brow) * 512 + m] = hv[r];
            if (t == T_STEPS - 1)
                out[OUT_N + 32768 + (size_t)brow * 512 + m] = hv[r];   // h_fin
        }
        // (8) prefetch t+2 (ybuf[(t+2)%3] fully consumed at epilogue(t-1); S1 fencing)
        if (t + 2 < T_STEPS) prefetch(t + 2, (t + 2) % 3);
    }

    // c_fin
    #pragma unroll
    for (int r = 0; r < 4; ++r)
        out[OUT_N + (size_t)(p * 32 + q * 16 + lq * 4 + r) * 512 + m] = creg[r];
}

// ---------------- launch ----------------

extern "C" void kernel_launch(void* const* d_in, const int* in_sizes, int n_in,
                              void* d_out, int out_size, void* d_ws, size_t ws_size,
                              hipStream_t stream) {
    const float* inputs = (const float*)d_in[0];
    const float* emb_s  = (const float*)d_in[1];
    const float* c0     = (const float*)d_in[2];
    const float* h0     = (const float*)d_in[3];
    const float* W_ioux = (const float*)d_in[4];  const float* b_ioux = (const float*)d_in[5];
    const float* W_iouh = (const float*)d_in[6];  const float* b_iouh = (const float*)d_in[7];
    const float* W_ious = (const float*)d_in[8];  const float* b_ious = (const float*)d_in[9];
    const float* W_fx   = (const float*)d_in[10]; const float* b_fx   = (const float*)d_in[11];
    const float* W_fh   = (const float*)d_in[12]; const float* b_fh   = (const float*)d_in[13];
    const float* W_wc   = (const float*)d_in[14]; const float* b_wc   = (const float*)d_in[15];
    float* out = (float*)d_out;

    char* ws = (char*)d_ws;
    size_t off = 0;
    auto alloc = [&](size_t bytes) -> void* {
        void* p = ws + off;
        off += (bytes + 255) & ~(size_t)255;
        return p;
    };
    unsigned short* ytile = (unsigned short*)alloc((size_t)NROWS * NBIG * 2);   // 100.7 MB
    unsigned short* xcat  = (unsigned short*)alloc((size_t)NROWS * KCAT * 2);   // 33.6 MB
    unsigned short* wbig  = (unsigned short*)alloc((size_t)NBIG * KCAT * 2);    // 6.3 MB
    float*          bbig  = (float*)alloc(NBIG * 4);
    unsigned short* w2    = (unsigned short*)alloc((size_t)W2ROWS * 512 * 2);   // 2.6 MB
    float*          b2    = (float*)alloc(W2ROWS * 4);
    unsigned short* hbuf0 = (unsigned short*)alloc(B_DIM * MDIM * 2);
    unsigned short* hbuf1 = (unsigned short*)alloc(B_DIM * MDIM * 2);
    int*            flags = (int*)alloc(128 * 32 * 4);                          // 16 KB

    pack_xcat<<<(NROWS * KCAT + 255) / 256, 256, 0, stream>>>(inputs, emb_s, xcat);
    pack_wbig<<<(NBIG * KCAT + 255) / 256, 256, 0, stream>>>(
        W_ioux, b_ioux, W_ious, b_ious, W_fx, b_fx, W_wc, b_wc, wbig, bbig);
    pack_w2<<<(W2ROWS * 512 + 255) / 256, 256, 0, stream>>>(W_iouh, b_iouh, W_fh, b_fh, w2, b2);
    init_state<<<(B_DIM * MDIM + 255) / 256, 256, 0, stream>>>(h0, hbuf0, flags);

    dim3 g1(NBIG / 128, NROWS / 128);
    gemm_big<<<g1, 256, 0, stream>>>(xcat, wbig, bbig, ytile);

    lstm_persist<<<NBLK2, 256, 0, stream>>>(ytile, w2, b2, c0, hbuf0, hbuf1, out, flags);
}